// Round 7
// baseline (8775.620 us; speedup 1.0000x reference)
//
#include <hip/hip_runtime.h>

#define B_  128
#define T_  2048
#define X_  128
#define H_  256
#define G3  768
#define NT  48   // 768/16

typedef _Float16 f16x8 __attribute__((ext_vector_type(8)));
typedef _Float16 f16x4 __attribute__((ext_vector_type(4)));
typedef float    f32x4 __attribute__((ext_vector_type(4)));

static __device__ __forceinline__ float sigm_f(float x) {
    // 1/(1+e^-x) = 1/(1+exp2(-x*log2e))
    return __builtin_amdgcn_rcpf(1.0f + __builtin_amdgcn_exp2f(-1.4426950408889634f * x));
}
static __device__ __forceinline__ float tanh_f(float x) {
    // tanh(x) = 1 - 2/(1+e^{2x})
    return 1.0f - 2.0f * __builtin_amdgcn_rcpf(1.0f + __builtin_amdgcn_exp2f(2.8853900817779268f * x));
}

// ---------------- kernel 0: convert weights fp32 -> fp16 ----------------
__global__ void cvt_w(const float* __restrict__ wih, const float* __restrict__ whh,
                      _Float16* __restrict__ wih16, _Float16* __restrict__ whh16) {
    int i = blockIdx.x * 256 + threadIdx.x;
    if (i < G3 * X_) wih16[i] = (_Float16)wih[i];
    if (i < G3 * H_) whh16[i] = (_Float16)whh[i];
}

// ---------------- kernel 1: x_proj chunk = input @ W_ih^T + b_ih --------
// Ring layout (fp16): [t_local][g(8)][nt(48)][n16(16)][b16(16)]
//   (a) each (t,g) block of 24 KiB is contiguous for global_load_lds staging
//   (b) inner [n16][b16] matches the MFMA C-fragment raster, so kernel-2
//       gate reads are one ds_read_b64 per lane.
__global__ __launch_bounds__(256) void xproj(const float* __restrict__ inp,
                                             const _Float16* __restrict__ wih16,
                                             const float* __restrict__ bih,
                                             _Float16* __restrict__ xp,
                                             int t_base) {
    const int tid  = threadIdx.x;
    const int lane = tid & 63;
    const int l15  = lane & 15, lhi = lane >> 4;
    const int wg   = blockIdx.x * 4 + (tid >> 6);
    const int g    = wg & 7;                        // batch group
    const int tl0  = (wg >> 3) * 4;                 // local time base (4 rows/wave)

    // A fragments: 4 M-tiles (4 t's, 16 b-rows each) x 4 K-steps, cvt f32->f16
    f16x8 a[4][4];
#pragma unroll
    for (int m = 0; m < 4; ++m) {
        const float* src = inp + ((size_t)(g * 16 + l15) * T_ + (t_base + tl0 + m)) * X_ + lhi * 8;
#pragma unroll
        for (int ks = 0; ks < 4; ++ks) {
            const float4 v0 = *(const float4*)(src + ks * 32);
            const float4 v1 = *(const float4*)(src + ks * 32 + 4);
            f16x8 av;
            av[0] = (_Float16)v0.x; av[1] = (_Float16)v0.y;
            av[2] = (_Float16)v0.z; av[3] = (_Float16)v0.w;
            av[4] = (_Float16)v1.x; av[5] = (_Float16)v1.y;
            av[6] = (_Float16)v1.z; av[7] = (_Float16)v1.w;
            a[m][ks] = av;
        }
    }

#pragma unroll 1
    for (int nt = 0; nt < NT; ++nt) {
        const float bias = bih[nt * 16 + l15];
        f32x4 acc[4];
#pragma unroll
        for (int m = 0; m < 4; ++m) acc[m] = f32x4{0.f, 0.f, 0.f, 0.f};
#pragma unroll
        for (int ks = 0; ks < 4; ++ks) {
            const f16x8 b = *(const f16x8*)(wih16 + (size_t)(nt * 16 + l15) * X_ + ks * 32 + lhi * 8);
#pragma unroll
            for (int m = 0; m < 4; ++m)
                acc[m] = __builtin_amdgcn_mfma_f32_16x16x32_f16(a[m][ks], b, acc[m], 0, 0, 0);
        }
#pragma unroll
        for (int m = 0; m < 4; ++m) {
            const size_t base = ((size_t)((tl0 + m) * 8 + g) * NT + nt) * 256;
            f16x4 v;
#pragma unroll
            for (int r = 0; r < 4; ++r) v[r] = (_Float16)(acc[m][r] + bias);
            // index = n16*16 + b16 : n16 = l15 (C col), b16 = lhi*4 + r (C row)
            *(f16x4*)(xp + base + l15 * 16 + lhi * 4) = v;
        }
    }
}

// ---------------- kernel 2: the GRU recurrence (one chunk) --------------
// 8 blocks x 512 threads; block g owns batch rows [16g, 16g+16).
// W_hh fp16 B-fragments resident in VGPRs (192/lane); h fp16 in LDS
// (XOR-swizzled chunks) for MFMA A-frags + in registers for the gates.
//
// x staging: wave w stages EXACTLY the three 1 KiB slices it alone consumes
// in the gate phase (q*8192 + w*1024, q=0..2).  Hence its own counted
// vmcnt is a complete readiness guarantee for its gate reads -- no
// cross-wave x dependency, no extra barrier (2 raw s_barrier per step).
//
// NOTE: the clamped redundant staging on the final iteration (tt = t) is
// load-bearing -- it keeps the outstanding-load count at 6 so the counted
// vmcnt(3) still drains x[t].  Do not "optimize" it away.
__global__ __launch_bounds__(512, 2) void gru(const _Float16* __restrict__ xp,
                                              const _Float16* __restrict__ whh16,
                                              const float* __restrict__ bhh,
                                              float* __restrict__ out,
                                              _Float16* __restrict__ h16,
                                              int t_base, int t_count, int write_out) {
    __shared__ _Float16 h_lds[16 * 256];        // 8 KiB, swizzled
    __shared__ _Float16 x_lds[2][NT * 256];     // 2 x 24 KiB double buffer

    const int tid  = threadIdx.x;
    const int lane = tid & 63;
    const int w    = tid >> 6;                  // wave 0..7
    const int l15  = lane & 15, lhi = lane >> 4;
    const int g    = blockIdx.x;                // 0..7

    // --- resident W_hh B-fragments + biases -----------------------------
    f16x8 wf[3][2][8];                          // [gate][sub][kstep]
    float bias[3][2];
#pragma unroll
    for (int gt = 0; gt < 3; ++gt)
#pragma unroll
        for (int s = 0; s < 2; ++s) {
            const int n = gt * 256 + w * 32 + s * 16 + l15;
            bias[gt][s] = bhh[n];
#pragma unroll
            for (int ks = 0; ks < 8; ++ks)
                wf[gt][s][ks] = *(const f16x8*)(whh16 + (size_t)n * H_ + ks * 32 + lhi * 8);
        }

    // --- h init: zeros (first chunk) or carried from h16 ----------------
    _Float16 h_own[2][4];
    if (t_base == 0) {
#pragma unroll
        for (int s = 0; s < 2; ++s)
#pragma unroll
            for (int r = 0; r < 4; ++r) h_own[s][r] = (_Float16)0.0f;
#pragma unroll
        for (int i = 0; i < 8; ++i) h_lds[tid * 8 + i] = (_Float16)0.0f;
    } else {
#pragma unroll
        for (int s = 0; s < 2; ++s) {
            const int j = w * 32 + s * 16 + l15;
#pragma unroll
            for (int r = 0; r < 4; ++r) {
                const int b = lhi * 4 + r;
                h_own[s][r] = h16[(size_t)(g * 16 + b) * H_ + j];
                h_lds[b * 256 + (((j >> 3) ^ (b & 7)) << 3) + (j & 7)] = h_own[s][r];
            }
        }
    }

    // --- prologue: stage x[t_local=0] into buffer 0 ---------------------
    {
        const char* gsrc = (const char*)(xp + (size_t)(0 * 8 + g) * (NT * 256));
        char* lbase = (char*)(&x_lds[0][0]);
#pragma unroll
        for (int q = 0; q < 3; ++q) {
            const int off = q * 8192 + w * 1024;
            __builtin_amdgcn_global_load_lds(
                (const __attribute__((address_space(1))) void*)(gsrc + off + lane * 16),
                (__attribute__((address_space(3))) void*)(lbase + off), 16, 0, 0);
        }
    }
    asm volatile("s_waitcnt vmcnt(0) lgkmcnt(0)" ::: "memory");
    __builtin_amdgcn_s_barrier();

    for (int t = 0; t < t_count; ++t) {
        const int cur = t & 1;

        // ---- issue stage of x[t+1] into the other buffer (async) ------
        {
            const int tt  = (t + 1 < t_count) ? (t + 1) : t;  // clamp at chunk end
            const char* gsrc = (const char*)(xp + (size_t)(tt * 8 + g) * (NT * 256));
            char* lbase = (char*)(&x_lds[cur ^ 1][0]);
#pragma unroll
            for (int q = 0; q < 3; ++q) {
                const int off = q * 8192 + w * 1024;
                __builtin_amdgcn_global_load_lds(
                    (const __attribute__((address_space(1))) void*)(gsrc + off + lane * 16),
                    (__attribute__((address_space(3))) void*)(lbase + off), 16, 0, 0);
            }
        }
        // wait for x[t] (issued last iter); the 3 newest (t+1) stay in flight
        asm volatile("s_waitcnt vmcnt(3)" ::: "memory");

        // ---- hp = h @ W_hh^T + b_hh (MFMA) ----------------------------
        f32x4 acc[3][2];
#pragma unroll
        for (int gt = 0; gt < 3; ++gt)
#pragma unroll
            for (int s = 0; s < 2; ++s)
                acc[gt][s] = f32x4{bias[gt][s], bias[gt][s], bias[gt][s], bias[gt][s]};

#pragma unroll
        for (int ks = 0; ks < 8; ++ks) {
            const int c = (ks * 4 + lhi) ^ (l15 & 7);   // swizzled 8-elem chunk
            const f16x8 af = *(const f16x8*)&h_lds[l15 * 256 + c * 8];
#pragma unroll
            for (int gt = 0; gt < 3; ++gt)
#pragma unroll
                for (int s = 0; s < 2; ++s)
                    acc[gt][s] = __builtin_amdgcn_mfma_f32_16x16x32_f16(af, wf[gt][s][ks], acc[gt][s], 0, 0, 0);
        }

        // ---- gates, fully in-register ---------------------------------
#pragma unroll
        for (int s = 0; s < 2; ++s) {
            const int sub = w * 2 + s;
            const f16x4 xr4 = *(const f16x4*)&x_lds[cur][(0  + sub) * 256 + l15 * 16 + lhi * 4];
            const f16x4 xz4 = *(const f16x4*)&x_lds[cur][(16 + sub) * 256 + l15 * 16 + lhi * 4];
            const f16x4 xn4 = *(const f16x4*)&x_lds[cur][(32 + sub) * 256 + l15 * 16 + lhi * 4];
#pragma unroll
            for (int r = 0; r < 4; ++r) {
                const float rg = sigm_f((float)xr4[r] + acc[0][s][r]);
                const float zg = sigm_f((float)xz4[r] + acc[1][s][r]);
                const float ng = tanh_f((float)xn4[r] + rg * acc[2][s][r]);
                h_own[s][r] = (_Float16)(zg * ((float)h_own[s][r] - ng) + ng);
            }
        }

        // all waves' LDS reads (h A-frags + x gates) drained, then overwrite h
        asm volatile("s_waitcnt lgkmcnt(0)" ::: "memory");
        __builtin_amdgcn_s_barrier();

#pragma unroll
        for (int s = 0; s < 2; ++s) {
            const int j = w * 32 + s * 16 + l15;
#pragma unroll
            for (int r = 0; r < 4; ++r) {
                const int b = lhi * 4 + r;
                h_lds[b * 256 + (((j >> 3) ^ (b & 7)) << 3) + (j & 7)] = h_own[s][r];
            }
        }
        asm volatile("s_waitcnt lgkmcnt(0)" ::: "memory");
        __builtin_amdgcn_s_barrier();
    }

    // ---- carry h to global; final chunk also writes fp32 output --------
#pragma unroll
    for (int s = 0; s < 2; ++s) {
        const int j = w * 32 + s * 16 + l15;
#pragma unroll
        for (int r = 0; r < 4; ++r) {
            const int b = lhi * 4 + r;
            h16[(size_t)(g * 16 + b) * H_ + j] = h_own[s][r];
            if (write_out) out[(size_t)(g * 16 + b) * H_ + j] = (float)h_own[s][r];
        }
    }
}

// ------------------------------------------------------------------------
extern "C" void kernel_launch(void* const* d_in, const int* in_sizes, int n_in,
                              void* d_out, int out_size, void* d_ws, size_t ws_size,
                              hipStream_t stream) {
    const float* inp = (const float*)d_in[0];
    const float* wih = (const float*)d_in[1];
    const float* whh = (const float*)d_in[2];
    const float* bih = (const float*)d_in[3];
    const float* bhh = (const float*)d_in[4];
    float* out = (float*)d_out;

    const size_t wih_b = (size_t)G3 * X_ * 2;   // 196,608
    const size_t whh_b = (size_t)G3 * H_ * 2;   // 393,216
    const size_t h_b   = (size_t)B_ * H_ * 2;   //  65,536
    const size_t fixed = wih_b + whh_b + h_b;
    const size_t per_t = (size_t)B_ * G3 * 2;   // 196,608 per time step

    // largest power-of-two chunk that fits the workspace (ring buffer)
    int cht = T_;
    while (cht > 8 && (size_t)cht * per_t + fixed > ws_size) cht >>= 1;
    if ((size_t)cht * per_t + fixed > ws_size) return;  // can't run

    char* ws = (char*)d_ws;
    _Float16* xpw   = (_Float16*)ws;
    _Float16* wih16 = (_Float16*)(ws + (size_t)cht * per_t);
    _Float16* whh16 = (_Float16*)(ws + (size_t)cht * per_t + wih_b);
    _Float16* h16   = (_Float16*)(ws + (size_t)cht * per_t + wih_b + whh_b);

    cvt_w<<<768, 256, 0, stream>>>(wih, whh, wih16, whh16);
    const int nch = T_ / cht;
    for (int c = 0; c < nch; ++c) {
        xproj<<<cht / 2, 256, 0, stream>>>(inp, wih16, bih, xpw, c * cht);
        gru<<<8, 512, 0, stream>>>(xpw, whh16, bhh, out, h16,
                                   c * cht, cht, (c == nch - 1) ? 1 : 0);
    }
}

// Round 8
// 4881.785 us; speedup vs baseline: 1.7976x; 1.7976x over previous
//
#include <hip/hip_runtime.h>

#define B_  128
#define T_  2048
#define X_  128
#define H_  256
#define G3  768
#define NT  48   // 768/16

typedef _Float16 f16x8 __attribute__((ext_vector_type(8)));
typedef _Float16 f16x4 __attribute__((ext_vector_type(4)));
typedef float    f32x4 __attribute__((ext_vector_type(4)));

static __device__ __forceinline__ float sigm_f(float x) {
    return __builtin_amdgcn_rcpf(1.0f + __builtin_amdgcn_exp2f(-1.4426950408889634f * x));
}
static __device__ __forceinline__ float tanh_f(float x) {
    return 1.0f - 2.0f * __builtin_amdgcn_rcpf(1.0f + __builtin_amdgcn_exp2f(2.8853900817779268f * x));
}

// ---------------- kernel 0: convert weights fp32 -> fp16 ----------------
__global__ void cvt_w(const float* __restrict__ wih, const float* __restrict__ whh,
                      _Float16* __restrict__ wih16, _Float16* __restrict__ whh16) {
    int i = blockIdx.x * 256 + threadIdx.x;
    if (i < G3 * X_) wih16[i] = (_Float16)wih[i];
    if (i < G3 * H_) whh16[i] = (_Float16)whh[i];
}

// ---------------- kernel 1: x_proj chunk = input @ W_ih^T + b_ih --------
// Ring layout (fp16): [t_local][g(8)][nt(48)][n16(16)][b16(16)]
__global__ __launch_bounds__(256) void xproj(const float* __restrict__ inp,
                                             const _Float16* __restrict__ wih16,
                                             const float* __restrict__ bih,
                                             _Float16* __restrict__ xp,
                                             int t_base) {
    const int tid  = threadIdx.x;
    const int lane = tid & 63;
    const int l15  = lane & 15, lhi = lane >> 4;
    const int wg   = blockIdx.x * 4 + (tid >> 6);
    const int g    = wg & 7;
    const int tl0  = (wg >> 3) * 4;

    f16x8 a[4][4];
#pragma unroll
    for (int m = 0; m < 4; ++m) {
        const float* src = inp + ((size_t)(g * 16 + l15) * T_ + (t_base + tl0 + m)) * X_ + lhi * 8;
#pragma unroll
        for (int ks = 0; ks < 4; ++ks) {
            const float4 v0 = *(const float4*)(src + ks * 32);
            const float4 v1 = *(const float4*)(src + ks * 32 + 4);
            f16x8 av;
            av[0] = (_Float16)v0.x; av[1] = (_Float16)v0.y;
            av[2] = (_Float16)v0.z; av[3] = (_Float16)v0.w;
            av[4] = (_Float16)v1.x; av[5] = (_Float16)v1.y;
            av[6] = (_Float16)v1.z; av[7] = (_Float16)v1.w;
            a[m][ks] = av;
        }
    }

#pragma unroll 1
    for (int nt = 0; nt < NT; ++nt) {
        const float bias = bih[nt * 16 + l15];
        f32x4 acc[4];
#pragma unroll
        for (int m = 0; m < 4; ++m) acc[m] = f32x4{0.f, 0.f, 0.f, 0.f};
#pragma unroll
        for (int ks = 0; ks < 4; ++ks) {
            const f16x8 b = *(const f16x8*)(wih16 + (size_t)(nt * 16 + l15) * X_ + ks * 32 + lhi * 8);
#pragma unroll
            for (int m = 0; m < 4; ++m)
                acc[m] = __builtin_amdgcn_mfma_f32_16x16x32_f16(a[m][ks], b, acc[m], 0, 0, 0);
        }
#pragma unroll
        for (int m = 0; m < 4; ++m) {
            const size_t base = ((size_t)((tl0 + m) * 8 + g) * NT + nt) * 256;
            f16x4 v;
#pragma unroll
            for (int r = 0; r < 4; ++r) v[r] = (_Float16)(acc[m][r] + bias);
            *(f16x4*)(xp + base + l15 * 16 + lhi * 4) = v;
        }
    }
}

// ---------------- kernel 2: the GRU recurrence (one chunk) --------------
// 8 blocks x 512 threads; block g owns batch rows [16g, 16g+16).
//
// ROUND-7 EVIDENCE: VGPR_Count=128 -> the 192-VGPR W_hh residency was
// spilled; weights were re-streamed every step (~6000 cyc/step from L2).
// FIX: split W_hh -- K-steps 0..5 (144 VGPR) in registers, K-steps 6..7
// (96 KiB, all 48 N-tiles) in LDS, filled once per launch.  New register
// budget ~205 < 256 cap, so residency is feasible for the allocator.
// LDS: 48 (x dbuf) + 8 (h) + 96 (W tail) = 152 KiB <= 160.
__global__ __launch_bounds__(512, 2) void gru(const _Float16* __restrict__ xp,
                                              const _Float16* __restrict__ whh16,
                                              const float* __restrict__ bhh,
                                              float* __restrict__ out,
                                              _Float16* __restrict__ h16,
                                              int t_base, int t_count, int write_out) {
    __shared__ _Float16 h_lds[16 * 256];        // 8 KiB, swizzled
    __shared__ _Float16 x_lds[2][NT * 256];     // 2 x 24 KiB double buffer
    __shared__ _Float16 w_lds[96 * 512];        // 96 KiB: W_hh K-steps 6..7

    const int tid  = threadIdx.x;
    const int lane = tid & 63;
    const int w    = tid >> 6;                  // wave 0..7
    const int l15  = lane & 15, lhi = lane >> 4;
    const int g    = blockIdx.x;                // 0..7

    // --- fill w_lds (cross-wave; visibility via prologue vmcnt(0)+barrier)
    // unit u = 1 KiB = one (nt, ks) B-fragment tile, laid out lane-linear.
#pragma unroll
    for (int i = 0; i < 12; ++i) {
        const int u  = i * 8 + w;               // 0..95
        const int nt = u >> 1;
        const int ks = 6 + (u & 1);
        const _Float16* src = whh16 + (size_t)(nt * 16 + l15) * H_ + ks * 32 + lhi * 8;
        __builtin_amdgcn_global_load_lds(
            (const __attribute__((address_space(1))) void*)src,
            (__attribute__((address_space(3))) void*)((char*)w_lds + u * 1024), 16, 0, 0);
    }

    // --- resident W_hh B-fragments (K-steps 0..5) + biases ---------------
    f16x8 wf[3][2][6];                          // 144 VGPR
    float bias[3][2];
#pragma unroll
    for (int gt = 0; gt < 3; ++gt)
#pragma unroll
        for (int s = 0; s < 2; ++s) {
            const int n = gt * 256 + w * 32 + s * 16 + l15;
            bias[gt][s] = bhh[n];
#pragma unroll
            for (int ks = 0; ks < 6; ++ks)
                wf[gt][s][ks] = *(const f16x8*)(whh16 + (size_t)n * H_ + ks * 32 + lhi * 8);
        }

    // --- h init: zeros (first chunk) or carried from h16 ----------------
    _Float16 h_own[2][4];
    if (t_base == 0) {
#pragma unroll
        for (int s = 0; s < 2; ++s)
#pragma unroll
            for (int r = 0; r < 4; ++r) h_own[s][r] = (_Float16)0.0f;
#pragma unroll
        for (int i = 0; i < 8; ++i) h_lds[tid * 8 + i] = (_Float16)0.0f;
    } else {
#pragma unroll
        for (int s = 0; s < 2; ++s) {
            const int j = w * 32 + s * 16 + l15;
#pragma unroll
            for (int r = 0; r < 4; ++r) {
                const int b = lhi * 4 + r;
                h_own[s][r] = h16[(size_t)(g * 16 + b) * H_ + j];
                h_lds[b * 256 + (((j >> 3) ^ (b & 7)) << 3) + (j & 7)] = h_own[s][r];
            }
        }
    }

    // --- prologue: stage x[t_local=0] into buffer 0 ---------------------
    // wave w stages exactly the three 1 KiB slices it alone gate-reads.
    const char* gsrc = (const char*)(xp + (size_t)g * (NT * 256));
    {
        char* lbase = (char*)(&x_lds[0][0]);
#pragma unroll
        for (int q = 0; q < 3; ++q) {
            const int off = q * 8192 + w * 1024;
            __builtin_amdgcn_global_load_lds(
                (const __attribute__((address_space(1))) void*)(gsrc + off + lane * 16),
                (__attribute__((address_space(3))) void*)(lbase + off), 16, 0, 0);
        }
    }
    asm volatile("s_waitcnt vmcnt(0) lgkmcnt(0)" ::: "memory");
    __builtin_amdgcn_s_barrier();

    for (int t = 0; t < t_count; ++t) {
        const int cur = t & 1;

        // ---- issue stage of x[t+1] (async); clamp keeps vmcnt math valid
        if (t + 1 < t_count) gsrc += (size_t)8 * NT * 256 * sizeof(_Float16);
        {
            char* lbase = (char*)(&x_lds[cur ^ 1][0]);
#pragma unroll
            for (int q = 0; q < 3; ++q) {
                const int off = q * 8192 + w * 1024;
                __builtin_amdgcn_global_load_lds(
                    (const __attribute__((address_space(1))) void*)(gsrc + off + lane * 16),
                    (__attribute__((address_space(3))) void*)(lbase + off), 16, 0, 0);
            }
        }
        // wait for x[t] (issued last iter); the 3 newest (t+1) stay in flight
        asm volatile("s_waitcnt vmcnt(3)" ::: "memory");

        // ---- hp = h @ W_hh^T + b_hh (MFMA) ----------------------------
        f32x4 acc[3][2];
#pragma unroll
        for (int gt = 0; gt < 3; ++gt)
#pragma unroll
            for (int s = 0; s < 2; ++s)
                acc[gt][s] = f32x4{bias[gt][s], bias[gt][s], bias[gt][s], bias[gt][s]};

#pragma unroll
        for (int ks = 0; ks < 8; ++ks) {
            const int c = (ks * 4 + lhi) ^ (l15 & 7);   // swizzled 8-elem chunk
            const f16x8 af = *(const f16x8*)&h_lds[l15 * 256 + c * 8];
#pragma unroll
            for (int gt = 0; gt < 3; ++gt)
#pragma unroll
                for (int s = 0; s < 2; ++s) {
                    f16x8 bf;
                    if (ks < 6) {
                        bf = wf[gt][s][ks];
                    } else {
                        const int u = (gt * 16 + w * 2 + s) * 2 + (ks - 6);
                        bf = *(const f16x8*)&w_lds[(u << 9) + lane * 8];
                    }
                    acc[gt][s] = __builtin_amdgcn_mfma_f32_16x16x32_f16(af, bf, acc[gt][s], 0, 0, 0);
                }
        }

        // ---- gates, fully in-register ---------------------------------
#pragma unroll
        for (int s = 0; s < 2; ++s) {
            const int sub = w * 2 + s;
            const f16x4 xr4 = *(const f16x4*)&x_lds[cur][(0  + sub) * 256 + l15 * 16 + lhi * 4];
            const f16x4 xz4 = *(const f16x4*)&x_lds[cur][(16 + sub) * 256 + l15 * 16 + lhi * 4];
            const f16x4 xn4 = *(const f16x4*)&x_lds[cur][(32 + sub) * 256 + l15 * 16 + lhi * 4];
#pragma unroll
            for (int r = 0; r < 4; ++r) {
                const float rg = sigm_f((float)xr4[r] + acc[0][s][r]);
                const float zg = sigm_f((float)xz4[r] + acc[1][s][r]);
                const float ng = tanh_f((float)xn4[r] + rg * acc[2][s][r]);
                h_own[s][r] = (_Float16)(zg * ((float)h_own[s][r] - ng) + ng);
            }
        }

        // all waves' LDS reads (h A-frags + x gates) drained, then overwrite h
        asm volatile("s_waitcnt lgkmcnt(0)" ::: "memory");
        __builtin_amdgcn_s_barrier();

#pragma unroll
        for (int s = 0; s < 2; ++s) {
            const int j = w * 32 + s * 16 + l15;
#pragma unroll
            for (int r = 0; r < 4; ++r) {
                const int b = lhi * 4 + r;
                h_lds[b * 256 + (((j >> 3) ^ (b & 7)) << 3) + (j & 7)] = h_own[s][r];
            }
        }
        asm volatile("s_waitcnt lgkmcnt(0)" ::: "memory");
        __builtin_amdgcn_s_barrier();
    }

    // ---- carry h to global; final chunk also writes fp32 output --------
#pragma unroll
    for (int s = 0; s < 2; ++s) {
        const int j = w * 32 + s * 16 + l15;
#pragma unroll
        for (int r = 0; r < 4; ++r) {
            const int b = lhi * 4 + r;
            h16[(size_t)(g * 16 + b) * H_ + j] = h_own[s][r];
            if (write_out) out[(size_t)(g * 16 + b) * H_ + j] = (float)h_own[s][r];
        }
    }
}

// ------------------------------------------------------------------------
extern "C" void kernel_launch(void* const* d_in, const int* in_sizes, int n_in,
                              void* d_out, int out_size, void* d_ws, size_t ws_size,
                              hipStream_t stream) {
    const float* inp = (const float*)d_in[0];
    const float* wih = (const float*)d_in[1];
    const float* whh = (const float*)d_in[2];
    const float* bih = (const float*)d_in[3];
    const float* bhh = (const float*)d_in[4];
    float* out = (float*)d_out;

    const size_t wih_b = (size_t)G3 * X_ * 2;
    const size_t whh_b = (size_t)G3 * H_ * 2;
    const size_t h_b   = (size_t)B_ * H_ * 2;
    const size_t fixed = wih_b + whh_b + h_b;
    const size_t per_t = (size_t)B_ * G3 * 2;

    int cht = T_;
    while (cht > 8 && (size_t)cht * per_t + fixed > ws_size) cht >>= 1;
    if ((size_t)cht * per_t + fixed > ws_size) return;

    char* ws = (char*)d_ws;
    _Float16* xpw   = (_Float16*)ws;
    _Float16* wih16 = (_Float16*)(ws + (size_t)cht * per_t);
    _Float16* whh16 = (_Float16*)(ws + (size_t)cht * per_t + wih_b);
    _Float16* h16   = (_Float16*)(ws + (size_t)cht * per_t + wih_b + whh_b);

    cvt_w<<<768, 256, 0, stream>>>(wih, whh, wih16, whh16);
    const int nch = T_ / cht;
    for (int c = 0; c < nch; ++c) {
        xproj<<<cht / 2, 256, 0, stream>>>(inp, wih16, bih, xpw, c * cht);
        gru<<<8, 512, 0, stream>>>(xpw, whh16, bhh, out, h16,
                                   c * cht, cht, (c == nch - 1) ? 1 : 0);
    }
}

// Round 10
// 4872.129 us; speedup vs baseline: 1.8012x; 1.0020x over previous
//
#include <hip/hip_runtime.h>

#define B_  128
#define T_  2048
#define X_  128
#define H_  256
#define G3  768
#define NT  48   // 768/16

typedef _Float16 f16x8 __attribute__((ext_vector_type(8)));
typedef _Float16 f16x4 __attribute__((ext_vector_type(4)));
typedef float    f32x4 __attribute__((ext_vector_type(4)));

static __device__ __forceinline__ float sigm_f(float x) {
    return __builtin_amdgcn_rcpf(1.0f + __builtin_amdgcn_exp2f(-1.4426950408889634f * x));
}
static __device__ __forceinline__ float tanh_f(float x) {
    return 1.0f - 2.0f * __builtin_amdgcn_rcpf(1.0f + __builtin_amdgcn_exp2f(2.8853900817779268f * x));
}

// ---------------- kernel 0: convert weights fp32 -> fp16 ----------------
__global__ void cvt_w(const float* __restrict__ wih, const float* __restrict__ whh,
                      _Float16* __restrict__ wih16, _Float16* __restrict__ whh16) {
    int i = blockIdx.x * 256 + threadIdx.x;
    if (i < G3 * X_) wih16[i] = (_Float16)wih[i];
    if (i < G3 * H_) whh16[i] = (_Float16)whh[i];
}

// ---------------- kernel 1: x_proj chunk = input @ W_ih^T + b_ih --------
// Ring layout (fp16): [t_local][g(8)][nt(48)][n16(16)][b16(16)]
__global__ __launch_bounds__(256) void xproj(const float* __restrict__ inp,
                                             const _Float16* __restrict__ wih16,
                                             const float* __restrict__ bih,
                                             _Float16* __restrict__ xp,
                                             int t_base) {
    const int tid  = threadIdx.x;
    const int lane = tid & 63;
    const int l15  = lane & 15, lhi = lane >> 4;
    const int wg   = blockIdx.x * 4 + (tid >> 6);
    const int g    = wg & 7;
    const int tl0  = (wg >> 3) * 4;

    f16x8 a[4][4];
#pragma unroll
    for (int m = 0; m < 4; ++m) {
        const float* src = inp + ((size_t)(g * 16 + l15) * T_ + (t_base + tl0 + m)) * X_ + lhi * 8;
#pragma unroll
        for (int ks = 0; ks < 4; ++ks) {
            const float4 v0 = *(const float4*)(src + ks * 32);
            const float4 v1 = *(const float4*)(src + ks * 32 + 4);
            f16x8 av;
            av[0] = (_Float16)v0.x; av[1] = (_Float16)v0.y;
            av[2] = (_Float16)v0.z; av[3] = (_Float16)v0.w;
            av[4] = (_Float16)v1.x; av[5] = (_Float16)v1.y;
            av[6] = (_Float16)v1.z; av[7] = (_Float16)v1.w;
            a[m][ks] = av;
        }
    }

#pragma unroll 1
    for (int nt = 0; nt < NT; ++nt) {
        const float bias = bih[nt * 16 + l15];
        f32x4 acc[4];
#pragma unroll
        for (int m = 0; m < 4; ++m) acc[m] = f32x4{0.f, 0.f, 0.f, 0.f};
#pragma unroll
        for (int ks = 0; ks < 4; ++ks) {
            const f16x8 b = *(const f16x8*)(wih16 + (size_t)(nt * 16 + l15) * X_ + ks * 32 + lhi * 8);
#pragma unroll
            for (int m = 0; m < 4; ++m)
                acc[m] = __builtin_amdgcn_mfma_f32_16x16x32_f16(a[m][ks], b, acc[m], 0, 0, 0);
        }
#pragma unroll
        for (int m = 0; m < 4; ++m) {
            const size_t base = ((size_t)((tl0 + m) * 8 + g) * NT + nt) * 256;
            f16x4 v;
#pragma unroll
            for (int r = 0; r < 4; ++r) v[r] = (_Float16)(acc[m][r] + bias);
            *(f16x4*)(xp + base + l15 * 16 + lhi * 4) = v;
        }
    }
}

// ---------------- kernel 2: the GRU recurrence (one chunk) --------------
// 8 blocks x 512 threads; block g owns batch rows [16g, 16g+16).
//
// ROUND-8 EVIDENCE: VGPR_Count=124 despite ~205 pressure and a 256 cap.
// Not a capacity spill: the AMDGPU allocator's occupancy heuristic targets
// >2 waves/EU (<=128 VGPR) because __launch_bounds__'s 2nd arg is only a
// MINIMUM, and "rematerializes" the loop-invariant wf loads from L2 every
// step (FETCH unchanged, VALUBusy 43% on-CU, MfmaUtil 28% -- reload-bound).
// FIX: amdgpu_waves_per_eu(2,2) pins the occupancy target to exactly 2
// waves/EU so the allocator budgets the full 256 VGPRs and keeps wf
// (144 VGPR) truly resident.
// W split: K-steps 0..5 in registers, K-steps 6..7 (96 KiB) in LDS.
// LDS: 48 (x dbuf) + 8 (h) + 96 (W tail) = 152 KiB <= 160.
__global__ __attribute__((amdgpu_flat_work_group_size(512, 512),
                          amdgpu_waves_per_eu(2, 2)))
void gru(const _Float16* __restrict__ xp,
         const _Float16* __restrict__ whh16,
         const float* __restrict__ bhh,
         float* __restrict__ out,
         _Float16* __restrict__ h16,
         int t_base, int t_count, int write_out) {
    __shared__ _Float16 h_lds[16 * 256];        // 8 KiB, swizzled
    __shared__ _Float16 x_lds[2][NT * 256];     // 2 x 24 KiB double buffer
    __shared__ _Float16 w_lds[96 * 512];        // 96 KiB: W_hh K-steps 6..7

    const int tid  = threadIdx.x;
    const int lane = tid & 63;
    const int w    = tid >> 6;                  // wave 0..7
    const int l15  = lane & 15, lhi = lane >> 4;
    const int g    = blockIdx.x;                // 0..7

    // --- fill w_lds (cross-wave; visibility via prologue vmcnt(0)+barrier)
#pragma unroll
    for (int i = 0; i < 12; ++i) {
        const int u  = i * 8 + w;               // 0..95
        const int nt = u >> 1;
        const int ks = 6 + (u & 1);
        const _Float16* src = whh16 + (size_t)(nt * 16 + l15) * H_ + ks * 32 + lhi * 8;
        __builtin_amdgcn_global_load_lds(
            (const __attribute__((address_space(1))) void*)src,
            (__attribute__((address_space(3))) void*)((char*)w_lds + u * 1024), 16, 0, 0);
    }

    // --- resident W_hh B-fragments (K-steps 0..5) + biases ---------------
    f16x8 wf[3][2][6];                          // 144 VGPR
    float bias[3][2];
#pragma unroll
    for (int gt = 0; gt < 3; ++gt)
#pragma unroll
        for (int s = 0; s < 2; ++s) {
            const int n = gt * 256 + w * 32 + s * 16 + l15;
            bias[gt][s] = bhh[n];
#pragma unroll
            for (int ks = 0; ks < 6; ++ks)
                wf[gt][s][ks] = *(const f16x8*)(whh16 + (size_t)n * H_ + ks * 32 + lhi * 8);
        }

    // --- h init: zeros (first chunk) or carried from h16 ----------------
    _Float16 h_own[2][4];
    if (t_base == 0) {
#pragma unroll
        for (int s = 0; s < 2; ++s)
#pragma unroll
            for (int r = 0; r < 4; ++r) h_own[s][r] = (_Float16)0.0f;
#pragma unroll
        for (int i = 0; i < 8; ++i) h_lds[tid * 8 + i] = (_Float16)0.0f;
    } else {
#pragma unroll
        for (int s = 0; s < 2; ++s) {
            const int j = w * 32 + s * 16 + l15;
#pragma unroll
            for (int r = 0; r < 4; ++r) {
                const int b = lhi * 4 + r;
                h_own[s][r] = h16[(size_t)(g * 16 + b) * H_ + j];
                h_lds[b * 256 + (((j >> 3) ^ (b & 7)) << 3) + (j & 7)] = h_own[s][r];
            }
        }
    }

    // --- prologue: stage x[t_local=0] into buffer 0 ---------------------
    // wave w stages exactly the three 1 KiB slices it alone gate-reads.
    const char* gsrc = (const char*)(xp + (size_t)g * (NT * 256));
    {
        char* lbase = (char*)(&x_lds[0][0]);
#pragma unroll
        for (int q = 0; q < 3; ++q) {
            const int off = q * 8192 + w * 1024;
            __builtin_amdgcn_global_load_lds(
                (const __attribute__((address_space(1))) void*)(gsrc + off + lane * 16),
                (__attribute__((address_space(3))) void*)(lbase + off), 16, 0, 0);
        }
    }
    asm volatile("s_waitcnt vmcnt(0) lgkmcnt(0)" ::: "memory");
    __builtin_amdgcn_s_barrier();

    for (int t = 0; t < t_count; ++t) {
        const int cur = t & 1;

        // ---- issue stage of x[t+1] (async); clamp keeps vmcnt math valid
        if (t + 1 < t_count) gsrc += (size_t)8 * NT * 256 * sizeof(_Float16);
        {
            char* lbase = (char*)(&x_lds[cur ^ 1][0]);
#pragma unroll
            for (int q = 0; q < 3; ++q) {
                const int off = q * 8192 + w * 1024;
                __builtin_amdgcn_global_load_lds(
                    (const __attribute__((address_space(1))) void*)(gsrc + off + lane * 16),
                    (__attribute__((address_space(3))) void*)(lbase + off), 16, 0, 0);
            }
        }
        // wait for x[t] (issued last iter); the 3 newest (t+1) stay in flight
        asm volatile("s_waitcnt vmcnt(3)" ::: "memory");

        // ---- hp = h @ W_hh^T + b_hh (MFMA) ----------------------------
        f32x4 acc[3][2];
#pragma unroll
        for (int gt = 0; gt < 3; ++gt)
#pragma unroll
            for (int s = 0; s < 2; ++s)
                acc[gt][s] = f32x4{bias[gt][s], bias[gt][s], bias[gt][s], bias[gt][s]};

#pragma unroll
        for (int ks = 0; ks < 8; ++ks) {
            const int c = (ks * 4 + lhi) ^ (l15 & 7);   // swizzled 8-elem chunk
            const f16x8 af = *(const f16x8*)&h_lds[l15 * 256 + c * 8];
#pragma unroll
            for (int gt = 0; gt < 3; ++gt)
#pragma unroll
                for (int s = 0; s < 2; ++s) {
                    f16x8 bf;
                    if (ks < 6) {
                        bf = wf[gt][s][ks];
                    } else {
                        const int u = (gt * 16 + w * 2 + s) * 2 + (ks - 6);
                        bf = *(const f16x8*)&w_lds[(u << 9) + lane * 8];
                    }
                    acc[gt][s] = __builtin_amdgcn_mfma_f32_16x16x32_f16(af, bf, acc[gt][s], 0, 0, 0);
                }
        }

        // ---- gates, fully in-register ---------------------------------
#pragma unroll
        for (int s = 0; s < 2; ++s) {
            const int sub = w * 2 + s;
            const f16x4 xr4 = *(const f16x4*)&x_lds[cur][(0  + sub) * 256 + l15 * 16 + lhi * 4];
            const f16x4 xz4 = *(const f16x4*)&x_lds[cur][(16 + sub) * 256 + l15 * 16 + lhi * 4];
            const f16x4 xn4 = *(const f16x4*)&x_lds[cur][(32 + sub) * 256 + l15 * 16 + lhi * 4];
#pragma unroll
            for (int r = 0; r < 4; ++r) {
                const float rg = sigm_f((float)xr4[r] + acc[0][s][r]);
                const float zg = sigm_f((float)xz4[r] + acc[1][s][r]);
                const float ng = tanh_f((float)xn4[r] + rg * acc[2][s][r]);
                h_own[s][r] = (_Float16)(zg * ((float)h_own[s][r] - ng) + ng);
            }
        }

        // all waves' LDS reads (h A-frags + x gates) drained, then overwrite h
        asm volatile("s_waitcnt lgkmcnt(0)" ::: "memory");
        __builtin_amdgcn_s_barrier();

#pragma unroll
        for (int s = 0; s < 2; ++s) {
            const int j = w * 32 + s * 16 + l15;
#pragma unroll
            for (int r = 0; r < 4; ++r) {
                const int b = lhi * 4 + r;
                h_lds[b * 256 + (((j >> 3) ^ (b & 7)) << 3) + (j & 7)] = h_own[s][r];
            }
        }
        asm volatile("s_waitcnt lgkmcnt(0)" ::: "memory");
        __builtin_amdgcn_s_barrier();
    }

    // ---- carry h to global; final chunk also writes fp32 output --------
#pragma unroll
    for (int s = 0; s < 2; ++s) {
        const int j = w * 32 + s * 16 + l15;
#pragma unroll
        for (int r = 0; r < 4; ++r) {
            const int b = lhi * 4 + r;
            h16[(size_t)(g * 16 + b) * H_ + j] = h_own[s][r];
            if (write_out) out[(size_t)(g * 16 + b) * H_ + j] = (float)h_own[s][r];
        }
    }
}

// ------------------------------------------------------------------------
extern "C" void kernel_launch(void* const* d_in, const int* in_sizes, int n_in,
                              void* d_out, int out_size, void* d_ws, size_t ws_size,
                              hipStream_t stream) {
    const float* inp = (const float*)d_in[0];
    const float* wih = (const float*)d_in[1];
    const float* whh = (const float*)d_in[2];
    const float* bih = (const float*)d_in[3];
    const float* bhh = (const float*)d_in[4];
    float* out = (float*)d_out;

    const size_t wih_b = (size_t)G3 * X_ * 2;
    const size_t whh_b = (size_t)G3 * H_ * 2;
    const size_t h_b   = (size_t)B_ * H_ * 2;
    const size_t fixed = wih_b + whh_b + h_b;
    const size_t per_t = (size_t)B_ * G3 * 2;

    int cht = T_;
    while (cht > 8 && (size_t)cht * per_t + fixed > ws_size) cht >>= 1;
    if ((size_t)cht * per_t + fixed > ws_size) return;

    char* ws = (char*)d_ws;
    _Float16* xpw   = (_Float16*)ws;
    _Float16* wih16 = (_Float16*)(ws + (size_t)cht * per_t);
    _Float16* whh16 = (_Float16*)(ws + (size_t)cht * per_t + wih_b);
    _Float16* h16   = (_Float16*)(ws + (size_t)cht * per_t + wih_b + whh_b);

    cvt_w<<<768, 256, 0, stream>>>(wih, whh, wih16, whh16);
    const int nch = T_ / cht;
    for (int c = 0; c < nch; ++c) {
        xproj<<<cht / 2, 256, 0, stream>>>(inp, wih16, bih, xpw, c * cht);
        gru<<<8, 512, 0, stream>>>(xpw, whh16, bhh, out, h16,
                                   c * cht, cht, (c == nch - 1) ? 1 : 0);
    }
}

// Round 12
// 4866.380 us; speedup vs baseline: 1.8033x; 1.0012x over previous
//
#include <hip/hip_runtime.h>

#define B_  128
#define T_  2048
#define X_  128
#define H_  256
#define G3  768
#define NT  48   // 768/16

typedef _Float16 f16x8 __attribute__((ext_vector_type(8)));
typedef _Float16 f16x4 __attribute__((ext_vector_type(4)));
typedef float    f32x4 __attribute__((ext_vector_type(4)));

static __device__ __forceinline__ float sigm_f(float x) {
    return __builtin_amdgcn_rcpf(1.0f + __builtin_amdgcn_exp2f(-1.4426950408889634f * x));
}
static __device__ __forceinline__ float tanh_f(float x) {
    return 1.0f - 2.0f * __builtin_amdgcn_rcpf(1.0f + __builtin_amdgcn_exp2f(2.8853900817779268f * x));
}

// ---------------- kernel 0: convert weights fp32 -> fp16 ----------------
__global__ void cvt_w(const float* __restrict__ wih, const float* __restrict__ whh,
                      _Float16* __restrict__ wih16, _Float16* __restrict__ whh16) {
    int i = blockIdx.x * 256 + threadIdx.x;
    if (i < G3 * X_) wih16[i] = (_Float16)wih[i];
    if (i < G3 * H_) whh16[i] = (_Float16)whh[i];
}

// ---------------- kernel 1: x_proj chunk = input @ W_ih^T + b_ih --------
// Ring layout (fp16): [t_local][g(8)][nt(48)][n16(16)][b16(16)]
__global__ __launch_bounds__(256) void xproj(const float* __restrict__ inp,
                                             const _Float16* __restrict__ wih16,
                                             const float* __restrict__ bih,
                                             _Float16* __restrict__ xp,
                                             int t_base) {
    const int tid  = threadIdx.x;
    const int lane = tid & 63;
    const int l15  = lane & 15, lhi = lane >> 4;
    const int wg   = blockIdx.x * 4 + (tid >> 6);
    const int g    = wg & 7;
    const int tl0  = (wg >> 3) * 4;

    f16x8 a[4][4];
#pragma unroll
    for (int m = 0; m < 4; ++m) {
        const float* src = inp + ((size_t)(g * 16 + l15) * T_ + (t_base + tl0 + m)) * X_ + lhi * 8;
#pragma unroll
        for (int ks = 0; ks < 4; ++ks) {
            const float4 v0 = *(const float4*)(src + ks * 32);
            const float4 v1 = *(const float4*)(src + ks * 32 + 4);
            f16x8 av;
            av[0] = (_Float16)v0.x; av[1] = (_Float16)v0.y;
            av[2] = (_Float16)v0.z; av[3] = (_Float16)v0.w;
            av[4] = (_Float16)v1.x; av[5] = (_Float16)v1.y;
            av[6] = (_Float16)v1.z; av[7] = (_Float16)v1.w;
            a[m][ks] = av;
        }
    }

#pragma unroll 1
    for (int nt = 0; nt < NT; ++nt) {
        const float bias = bih[nt * 16 + l15];
        f32x4 acc[4];
#pragma unroll
        for (int m = 0; m < 4; ++m) acc[m] = f32x4{0.f, 0.f, 0.f, 0.f};
#pragma unroll
        for (int ks = 0; ks < 4; ++ks) {
            const f16x8 b = *(const f16x8*)(wih16 + (size_t)(nt * 16 + l15) * X_ + ks * 32 + lhi * 8);
#pragma unroll
            for (int m = 0; m < 4; ++m)
                acc[m] = __builtin_amdgcn_mfma_f32_16x16x32_f16(a[m][ks], b, acc[m], 0, 0, 0);
        }
#pragma unroll
        for (int m = 0; m < 4; ++m) {
            const size_t base = ((size_t)((tl0 + m) * 8 + g) * NT + nt) * 256;
            f16x4 v;
#pragma unroll
            for (int r = 0; r < 4; ++r) v[r] = (_Float16)(acc[m][r] + bias);
            *(f16x4*)(xp + base + l15 * 16 + lhi * 4) = v;
        }
    }
}

// ---------------- kernel 2: the GRU recurrence (one chunk) --------------
// 8 blocks x 512 threads; block g owns batch rows [16g, 16g+16).
//
// ROUND-8/10 EVIDENCE: VGPR_Count=124 both with __launch_bounds__(512,2)
// and with amdgpu_waves_per_eu(2,2) -- identical codegen.  The 36
// loop-invariant wf loads are SUNK back into the loop by a pressure
// heuristic that attributes don't control, re-streaming 288 KB/step from
// L2 (~4600 cyc at the ~64 B/cyc per-CU return path; matches the 5350
// cyc/step observed).
// FIX: empty inline-asm "+v" pins on every wf fragment INSIDE the t-loop.
// Each fragment is thereby "redefined" per iteration, so re-loading from
// memory is no longer a legal materialization -- the values must stay in
// registers (or spill to scratch, which would be visible as VGPR~256 +
// scratch traffic).  Pressure ~228 fits the 256-VGPR budget at 2 waves/EU
// (LDS already caps occupancy at 1 block/CU), so no spill is expected.
// W split: K-steps 0..5 in registers (144 VGPR), K-steps 6..7 in LDS.
// LDS: 48 (x dbuf) + 8 (h) + 96 (W tail) = 152 KiB <= 160.
__global__ __attribute__((amdgpu_flat_work_group_size(512, 512),
                          amdgpu_waves_per_eu(2, 2)))
void gru(const _Float16* __restrict__ xp,
         const _Float16* __restrict__ whh16,
         const float* __restrict__ bhh,
         float* __restrict__ out,
         _Float16* __restrict__ h16,
         int t_base, int t_count, int write_out) {
    __shared__ _Float16 h_lds[16 * 256];        // 8 KiB, swizzled
    __shared__ _Float16 x_lds[2][NT * 256];     // 2 x 24 KiB double buffer
    __shared__ _Float16 w_lds[96 * 512];        // 96 KiB: W_hh K-steps 6..7

    const int tid  = threadIdx.x;
    const int lane = tid & 63;
    const int w    = tid >> 6;                  // wave 0..7
    const int l15  = lane & 15, lhi = lane >> 4;
    const int g    = blockIdx.x;                // 0..7

    // --- fill w_lds (cross-wave; visibility via prologue vmcnt(0)+barrier)
#pragma unroll
    for (int i = 0; i < 12; ++i) {
        const int u  = i * 8 + w;               // 0..95
        const int nt = u >> 1;
        const int ks = 6 + (u & 1);
        const _Float16* src = whh16 + (size_t)(nt * 16 + l15) * H_ + ks * 32 + lhi * 8;
        __builtin_amdgcn_global_load_lds(
            (const __attribute__((address_space(1))) void*)src,
            (__attribute__((address_space(3))) void*)((char*)w_lds + u * 1024), 16, 0, 0);
    }

    // --- resident W_hh B-fragments (K-steps 0..5) + biases ---------------
    f16x8 wf[3][2][6];                          // 144 VGPR, pinned in-loop
    float bias[3][2];
#pragma unroll
    for (int gt = 0; gt < 3; ++gt)
#pragma unroll
        for (int s = 0; s < 2; ++s) {
            const int n = gt * 256 + w * 32 + s * 16 + l15;
            bias[gt][s] = bhh[n];
#pragma unroll
            for (int ks = 0; ks < 6; ++ks)
                wf[gt][s][ks] = *(const f16x8*)(whh16 + (size_t)n * H_ + ks * 32 + lhi * 8);
        }

    // --- h init: zeros (first chunk) or carried from h16 ----------------
    _Float16 h_own[2][4];
    if (t_base == 0) {
#pragma unroll
        for (int s = 0; s < 2; ++s)
#pragma unroll
            for (int r = 0; r < 4; ++r) h_own[s][r] = (_Float16)0.0f;
#pragma unroll
        for (int i = 0; i < 8; ++i) h_lds[tid * 8 + i] = (_Float16)0.0f;
    } else {
#pragma unroll
        for (int s = 0; s < 2; ++s) {
            const int j = w * 32 + s * 16 + l15;
#pragma unroll
            for (int r = 0; r < 4; ++r) {
                const int b = lhi * 4 + r;
                h_own[s][r] = h16[(size_t)(g * 16 + b) * H_ + j];
                h_lds[b * 256 + (((j >> 3) ^ (b & 7)) << 3) + (j & 7)] = h_own[s][r];
            }
        }
    }

    // --- prologue: stage x[t_local=0] into buffer 0 ---------------------
    // wave w stages exactly the three 1 KiB slices it alone gate-reads.
    const char* gsrc = (const char*)(xp + (size_t)g * (NT * 256));
    {
        char* lbase = (char*)(&x_lds[0][0]);
#pragma unroll
        for (int q = 0; q < 3; ++q) {
            const int off = q * 8192 + w * 1024;
            __builtin_amdgcn_global_load_lds(
                (const __attribute__((address_space(1))) void*)(gsrc + off + lane * 16),
                (__attribute__((address_space(3))) void*)(lbase + off), 16, 0, 0);
        }
    }
    asm volatile("s_waitcnt vmcnt(0) lgkmcnt(0)" ::: "memory");
    __builtin_amdgcn_s_barrier();

    for (int t = 0; t < t_count; ++t) {
        const int cur = t & 1;

        // ---- residency pin: wf is "redefined" each iteration, so the
        // compiler cannot sink/remat its loads into the loop.  Emits no
        // instructions; register-allocation effect only.
#pragma unroll
        for (int gt = 0; gt < 3; ++gt)
#pragma unroll
            for (int s = 0; s < 2; ++s)
#pragma unroll
                for (int ks = 0; ks < 6; ++ks)
                    asm volatile("" : "+v"(wf[gt][s][ks]));

        // ---- issue stage of x[t+1] (async); clamp keeps vmcnt math valid
        if (t + 1 < t_count) gsrc += (size_t)8 * NT * 256 * sizeof(_Float16);
        {
            char* lbase = (char*)(&x_lds[cur ^ 1][0]);
#pragma unroll
            for (int q = 0; q < 3; ++q) {
                const int off = q * 8192 + w * 1024;
                __builtin_amdgcn_global_load_lds(
                    (const __attribute__((address_space(1))) void*)(gsrc + off + lane * 16),
                    (__attribute__((address_space(3))) void*)(lbase + off), 16, 0, 0);
            }
        }
        // wait for x[t] (issued last iter); the 3 newest (t+1) stay in flight
        asm volatile("s_waitcnt vmcnt(3)" ::: "memory");

        // ---- hp = h @ W_hh^T + b_hh (MFMA) ----------------------------
        f32x4 acc[3][2];
#pragma unroll
        for (int gt = 0; gt < 3; ++gt)
#pragma unroll
            for (int s = 0; s < 2; ++s)
                acc[gt][s] = f32x4{bias[gt][s], bias[gt][s], bias[gt][s], bias[gt][s]};

#pragma unroll
        for (int ks = 0; ks < 8; ++ks) {
            const int c = (ks * 4 + lhi) ^ (l15 & 7);   // swizzled 8-elem chunk
            const f16x8 af = *(const f16x8*)&h_lds[l15 * 256 + c * 8];
#pragma unroll
            for (int gt = 0; gt < 3; ++gt)
#pragma unroll
                for (int s = 0; s < 2; ++s) {
                    f16x8 bf;
                    if (ks < 6) {
                        bf = wf[gt][s][ks];
                    } else {
                        const int u = (gt * 16 + w * 2 + s) * 2 + (ks - 6);
                        bf = *(const f16x8*)&w_lds[(u << 9) + lane * 8];
                    }
                    acc[gt][s] = __builtin_amdgcn_mfma_f32_16x16x32_f16(af, bf, acc[gt][s], 0, 0, 0);
                }
        }

        // ---- gates, fully in-register ---------------------------------
#pragma unroll
        for (int s = 0; s < 2; ++s) {
            const int sub = w * 2 + s;
            const f16x4 xr4 = *(const f16x4*)&x_lds[cur][(0  + sub) * 256 + l15 * 16 + lhi * 4];
            const f16x4 xz4 = *(const f16x4*)&x_lds[cur][(16 + sub) * 256 + l15 * 16 + lhi * 4];
            const f16x4 xn4 = *(const f16x4*)&x_lds[cur][(32 + sub) * 256 + l15 * 16 + lhi * 4];
#pragma unroll
            for (int r = 0; r < 4; ++r) {
                const float rg = sigm_f((float)xr4[r] + acc[0][s][r]);
                const float zg = sigm_f((float)xz4[r] + acc[1][s][r]);
                const float ng = tanh_f((float)xn4[r] + rg * acc[2][s][r]);
                h_own[s][r] = (_Float16)(zg * ((float)h_own[s][r] - ng) + ng);
            }
        }

        // all waves' LDS reads (h A-frags + x gates) drained, then overwrite h
        asm volatile("s_waitcnt lgkmcnt(0)" ::: "memory");
        __builtin_amdgcn_s_barrier();

#pragma unroll
        for (int s = 0; s < 2; ++s) {
            const int j = w * 32 + s * 16 + l15;
#pragma unroll
            for (int r = 0; r < 4; ++r) {
                const int b = lhi * 4 + r;
                h_lds[b * 256 + (((j >> 3) ^ (b & 7)) << 3) + (j & 7)] = h_own[s][r];
            }
        }
        asm volatile("s_waitcnt lgkmcnt(0)" ::: "memory");
        __builtin_amdgcn_s_barrier();
    }

    // ---- carry h to global; final chunk also writes fp32 output --------
#pragma unroll
    for (int s = 0; s < 2; ++s) {
        const int j = w * 32 + s * 16 + l15;
#pragma unroll
        for (int r = 0; r < 4; ++r) {
            const int b = lhi * 4 + r;
            h16[(size_t)(g * 16 + b) * H_ + j] = h_own[s][r];
            if (write_out) out[(size_t)(g * 16 + b) * H_ + j] = (float)h_own[s][r];
        }
    }
}

// ------------------------------------------------------------------------
extern "C" void kernel_launch(void* const* d_in, const int* in_sizes, int n_in,
                              void* d_out, int out_size, void* d_ws, size_t ws_size,
                              hipStream_t stream) {
    const float* inp = (const float*)d_in[0];
    const float* wih = (const float*)d_in[1];
    const float* whh = (const float*)d_in[2];
    const float* bih = (const float*)d_in[3];
    const float* bhh = (const float*)d_in[4];
    float* out = (float*)d_out;

    const size_t wih_b = (size_t)G3 * X_ * 2;
    const size_t whh_b = (size_t)G3 * H_ * 2;
    const size_t h_b   = (size_t)B_ * H_ * 2;
    const size_t fixed = wih_b + whh_b + h_b;
    const size_t per_t = (size_t)B_ * G3 * 2;

    int cht = T_;
    while (cht > 8 && (size_t)cht * per_t + fixed > ws_size) cht >>= 1;
    if ((size_t)cht * per_t + fixed > ws_size) return;

    char* ws = (char*)d_ws;
    _Float16* xpw   = (_Float16*)ws;
    _Float16* wih16 = (_Float16*)(ws + (size_t)cht * per_t);
    _Float16* whh16 = (_Float16*)(ws + (size_t)cht * per_t + wih_b);
    _Float16* h16   = (_Float16*)(ws + (size_t)cht * per_t + wih_b + whh_b);

    cvt_w<<<768, 256, 0, stream>>>(wih, whh, wih16, whh16);
    const int nch = T_ / cht;
    for (int c = 0; c < nch; ++c) {
        xproj<<<cht / 2, 256, 0, stream>>>(inp, wih16, bih, xpw, c * cht);
        gru<<<8, 512, 0, stream>>>(xpw, whh16, bhh, out, h16,
                                   c * cht, cht, (c == nch - 1) ? 1 : 0);
    }
}